// Round 11
// baseline (137.299 us; speedup 1.0000x reference)
//
#include <hip/hip_runtime.h>
#include <hip/hip_bf16.h>

#define BM 128
#define BN 64
#define HD 64
#define LQ 2048
#define SD 72

typedef __attribute__((ext_vector_type(8))) short short8;
typedef __attribute__((ext_vector_type(16))) float f32x16;

// Q pre-scale: 1/sqrt(16) * log2(e) -> scores in log2 domain
#define QSCALE 0.360673760222241f

// workspace: KF | VF, each bf16 [32 heads][64 ch][4 units][64 lanes][8] = 32*2048*64
#define WS_HALF  ((size_t)32 * 2048 * 64)           // elements (ushort)
#define WS_NEEDED (2 * WS_HALF * sizeof(unsigned short))

static __device__ __forceinline__ unsigned pk2(float a, float b) {
    union { __hip_bfloat162 h2; unsigned u; } c;
    c.h2 = __float22bfloat162_rn(make_float2(a, b));   // v_cvt_pk_bf16_f32
    return c.u;
}

// ---------------- prepass: K,V -> bf16 fragment-ready layout (verified R7/R8) ----------------
// KF unit (ch, ks, lane): K[ch*32 + (lane&31)][ks*16 + (lane>>5)*8 .. +8]
// VF unit (ch, u=s*2+dg, lane): V^T[dg*32+(lane&31)][ch*32 + s*16 + (lane>>5)*8 .. +8]
__global__ __launch_bounds__(256)
void prep(const float* __restrict__ Kg, const float* __restrict__ Vg,
          unsigned short* __restrict__ KF, unsigned short* __restrict__ VF) {
    __shared__ unsigned short sK2[64][72];
    __shared__ unsigned short sV2[64][72];
    const int t  = threadIdx.x;
    const int bx = blockIdx.x;
    const int bh = bx >> 5;
    const int c  = bx & 31;
    const size_t ibase = (size_t)bh * (LQ * HD) + (size_t)c * 64 * HD;
    const int r  = t >> 4;
    const int c4 = (t & 15) * 4;

#pragma unroll
    for (int p = 0; p < 4; ++p) {
        const int row = p * 16 + r;
        const float4 kv4 = *(const float4*)(Kg + ibase + (size_t)row * HD + c4);
        uint2 ku; ku.x = pk2(kv4.x, kv4.y); ku.y = pk2(kv4.z, kv4.w);
        *(uint2*)&sK2[row][c4] = ku;
        const float4 vv4 = *(const float4*)(Vg + ibase + (size_t)row * HD + c4);
        const unsigned u0 = pk2(vv4.x, vv4.y);
        const unsigned u1 = pk2(vv4.z, vv4.w);
        sV2[c4 + 0][row] = (unsigned short)(u0 & 0xffff);
        sV2[c4 + 1][row] = (unsigned short)(u0 >> 16);
        sV2[c4 + 2][row] = (unsigned short)(u1 & 0xffff);
        sV2[c4 + 3][row] = (unsigned short)(u1 >> 16);
    }
    __syncthreads();

    const int lane = t & 63;
    const int u    = t >> 6;
    const int l31  = lane & 31;
    const int hh   = lane >> 5;
#pragma unroll
    for (int e = 0; e < 2; ++e) {
        const int ch = 2 * c + e;
        const size_t ob = ((size_t)(bh * 64 + ch) * 4 + u) * 512 + lane * 8;
        *(uint4*)&KF[ob] = *(const uint4*)&sK2[e * 32 + l31][u * 16 + hh * 8];
        *(uint4*)&VF[ob] = *(const uint4*)&sV2[(u & 1) * 32 + l31][e * 32 + (u >> 1) * 16 + hh * 8];
    }
}

// ---------------- main: equal-length waves (paired q-blocks, mod-4 kv split) ----------------
// Wave (qg, kp) of block (bh, g): segment 0 -> q-block j = 2g+qg, segment 1 -> j = 63-(2g+qg).
// Within a segment the wave handles chunks ch ≡ kp (mod 4), ch <= j.
// Every wave: 16-17 chunks total -> full 4-wave/SIMD TLP for the whole makespan.
__global__ __launch_bounds__(512, 4)
void fa_main(const float* __restrict__ Qg,
             const unsigned short* __restrict__ KF,
             const unsigned short* __restrict__ VF,
             float* __restrict__ Og) {
    // LDS for the 4-way kv-residue combine: [2 qg][3 writers][64 d][32 q]
    __shared__ float fx[2 * 3 * 64 * 32];
    __shared__ float fla[2 * 3 * 32];

    const int t    = threadIdx.x;
    const int w    = t >> 6;            // wave 0..7
    const int lane = t & 63;
    const int h    = lane >> 5;
    const int l31  = lane & 31;
    const int qg   = w & 1;             // q-pair slot within block
    const int kp   = w >> 1;            // kv residue 0..3 (chunks ch ≡ kp mod 4)

    const int bx  = blockIdx.x;
    const int bh  = bx & 31;            // head; pair {bx, bx+256} shares head
    const int g   = bx >> 5;            // 0..15
    const int js  = 2 * g + qg;         // small q-block 0..31; large = 63-js

    const size_t base = (size_t)bh * (LQ * HD);
    const unsigned short* KFh = KF + (size_t)bh * 131072 + lane * 8;
    const unsigned short* VFh = VF + (size_t)bh * 131072 + lane * 8;

    // pipeline state
    short8 qreg[4], ak[4], av[4], pf[2];
    f32x16 accS, accO[2];
    float lsum0, lsum1;
    int j, qrow;

    auto loadK = [&](int ch) {
        const unsigned short* p = KFh + (size_t)ch * 2048;
        ak[0] = *(const short8*)(p);
        ak[1] = *(const short8*)(p + 512);
        ak[2] = *(const short8*)(p + 1024);
        ak[3] = *(const short8*)(p + 1536);
    };
    auto loadV = [&](int ch) {
        const unsigned short* p = VFh + (size_t)ch * 2048;
        av[0] = *(const short8*)(p);
        av[1] = *(const short8*)(p + 512);
        av[2] = *(const short8*)(p + 1024);
        av[3] = *(const short8*)(p + 1536);
    };
    auto qkt = [&]() {                  // S^T[32kv][32q] = K * Q^T (log2 domain)
#pragma unroll
        for (int r = 0; r < 16; ++r) accS[r] = 0.f;
        __builtin_amdgcn_s_setprio(1);
#pragma unroll
        for (int ks = 0; ks < 4; ++ks)
            accS = __builtin_amdgcn_mfma_f32_32x32x16_bf16(ak[ks], qreg[ks], accS, 0, 0, 0);
        __builtin_amdgcn_s_setprio(0);
    };
    auto smpk = [&](int pc) {           // mask(if diagonal) + exp2 + denom + pack -> pf
        if (pc == j) {
            const int kvb = pc * 32 + 4 * h;
#pragma unroll
            for (int r = 0; r < 16; ++r) {
                const int kv = kvb + (r & 3) + 8 * (r >> 2);
                if (kv > qrow) accS[r] = -1e30f;
            }
        }
#pragma unroll
        for (int r = 0; r < 16; ++r) {
            const float p = __builtin_amdgcn_exp2f(accS[r]);
            accS[r] = p;
            if (r & 1) lsum1 += p; else lsum0 += p;
        }
#pragma unroll
        for (int s = 0; s < 2; ++s) {
            const int rb = s * 8;
            const unsigned a0 = pk2(accS[rb + 0], accS[rb + 1]);
            const unsigned b0 = pk2(accS[rb + 4], accS[rb + 5]);
            const unsigned a1 = pk2(accS[rb + 2], accS[rb + 3]);
            const unsigned b1 = pk2(accS[rb + 6], accS[rb + 7]);
            const auto r02 = __builtin_amdgcn_permlane32_swap(a0, b0, 0, 0);
            const auto r13 = __builtin_amdgcn_permlane32_swap(a1, b1, 0, 0);
            union { unsigned u[4]; short8 s8; } pu;
            pu.u[0] = r02[0]; pu.u[1] = r13[0]; pu.u[2] = r02[1]; pu.u[3] = r13[1];
            pf[s] = pu.s8;
        }
    };
    auto pv = [&]() {                   // O^T += V^T * P^T
        __builtin_amdgcn_s_setprio(1);
#pragma unroll
        for (int s = 0; s < 2; ++s)
#pragma unroll
            for (int dg = 0; dg < 2; ++dg)
                accO[dg] = __builtin_amdgcn_mfma_f32_32x32x16_bf16(av[s * 2 + dg], pf[s], accO[dg], 0, 0, 0);
        __builtin_amdgcn_s_setprio(0);
    };

#pragma unroll 1
    for (int seg = 0; seg < 2; ++seg) {
        j    = seg ? (63 - js) : js;
        qrow = j * 32 + l31;

        // ---- Q fragments for this segment (direct fp32, pre-scaled) ----
        {
            const float* Qrow = Qg + base + (size_t)qrow * HD;
#pragma unroll
            for (int ks = 0; ks < 4; ++ks) {
                const float4 a = *(const float4*)(Qrow + ks * 16 + h * 8);
                const float4 b = *(const float4*)(Qrow + ks * 16 + h * 8 + 4);
                union { unsigned u[4]; short8 s8; } qu;
                qu.u[0] = pk2(a.x * QSCALE, a.y * QSCALE);
                qu.u[1] = pk2(a.z * QSCALE, a.w * QSCALE);
                qu.u[2] = pk2(b.x * QSCALE, b.y * QSCALE);
                qu.u[3] = pk2(b.z * QSCALE, b.w * QSCALE);
                qreg[ks] = qu.s8;
            }
        }
#pragma unroll
        for (int r = 0; r < 16; ++r) { accO[0][r] = 0.f; accO[1][r] = 0.f; }
        lsum0 = 0.f; lsum1 = 0.f;

        // ---- deferred-softmax pipeline over ch ≡ kp (mod 4) ----
        int ch = kp;
        if (ch <= j) {
            loadK(ch);
            loadV(ch);
            qkt();
            int pc = ch;
            ch += 4;
            while (ch <= j) {
                loadK(ch);
                __builtin_amdgcn_sched_barrier(0);
                smpk(pc);
                pv();
                loadV(ch);
                __builtin_amdgcn_sched_barrier(0);
                qkt();
                pc = ch;
                ch += 4;
            }
            smpk(pc);                    // diagonal mask applies on the last chunk of wave kp = j&3
            pv();
        }

        // ---- epilogue: 4-way residue combine via LDS; kp==0 writes O ----
        float lsum = lsum0 + lsum1;
        lsum += __shfl_xor(lsum, 32);
        if (kp != 0) {
            const int kpi = kp - 1;
#pragma unroll
            for (int dg = 0; dg < 2; ++dg) {
#pragma unroll
                for (int r = 0; r < 16; ++r) {
                    const int d = dg * 32 + (r & 3) + 8 * (r >> 2) + 4 * h;
                    fx[(((qg * 3 + kpi) * 64) + d) * 32 + l31] = accO[dg][r];
                }
            }
            if (h == 0) fla[(qg * 3 + kpi) * 32 + l31] = lsum;
        }
        __syncthreads();
        if (kp == 0) {
            const float den = lsum + fla[(qg * 3 + 0) * 32 + l31]
                                   + fla[(qg * 3 + 1) * 32 + l31]
                                   + fla[(qg * 3 + 2) * 32 + l31];
            const float inv = 1.0f / den;
            float* Op = Og + base + (size_t)qrow * HD;
#pragma unroll
            for (int dg = 0; dg < 2; ++dg) {
#pragma unroll
                for (int rq = 0; rq < 4; ++rq) {
                    const int d = dg * 32 + 8 * rq + 4 * h;
                    const float* f0 = &fx[(((qg * 3 + 0) * 64) + d) * 32 + l31];
                    const float* f1 = &fx[(((qg * 3 + 1) * 64) + d) * 32 + l31];
                    const float* f2 = &fx[(((qg * 3 + 2) * 64) + d) * 32 + l31];
                    float4 o;
                    o.x = (accO[dg][rq * 4 + 0] + f0[0]  + f1[0]  + f2[0])  * inv;
                    o.y = (accO[dg][rq * 4 + 1] + f0[32] + f1[32] + f2[32]) * inv;
                    o.z = (accO[dg][rq * 4 + 2] + f0[64] + f1[64] + f2[64]) * inv;
                    o.w = (accO[dg][rq * 4 + 3] + f0[96] + f1[96] + f2[96]) * inv;
                    *(float4*)(Op + d) = o;
                }
            }
        }
        __syncthreads();                 // fx reusable by next segment
    }
}

// ---------------- fallback: R1 kernel (verified 54.6 us), used if ws too small ----------------
__global__ __launch_bounds__(512, 4)
void fa_fwd(const float* __restrict__ Qg,
            const float* __restrict__ Kg,
            const float* __restrict__ Vg,
            float* __restrict__ Og) {
    __shared__ __align__(16) unsigned short lds[(2 * BN + 2 * HD) * SD];
    typedef unsigned short KT[BN][SD];
    typedef unsigned short VT[HD][SD];
    KT* sK  = (KT*)lds;
    VT* sVt = (VT*)(lds + 2 * BN * SD);

    const int t    = threadIdx.x;
    const int w    = t >> 6;
    const int lane = t & 63;
    const int h    = lane >> 5;
    const int l31  = lane & 31;
    const int qd   = lane >> 4;
    const int qg   = w & 3;
    const int kh   = w >> 2;

    const int bx  = blockIdx.x;
    const int idx = (bx >> 5) & 7;
    const int qt  = (bx & 256) ? idx : (15 - idx);
    const int bh  = bx & 31;
    const int q0  = qt * BM;

    const size_t base = (size_t)bh * (LQ * HD);
    const float* Qp = Qg + base + (size_t)q0 * HD;
    const float* Kp = Kg + base;
    const float* Vp = Vg + base;

    const int r0 = t >> 4;
    const int c4 = (t & 15) * 4;
    const int RA = w * 4;

    {
        unsigned short (*sQ)[SD] = (unsigned short (*)[SD])lds;
#pragma unroll
        for (int p = 0; p < 4; ++p) {
            const int r = p * 32 + r0;
            const float4 v = *(const float4*)(Qp + (size_t)r * HD + c4);
            uint2 u;
            u.x = pk2(v.x * QSCALE, v.y * QSCALE);
            u.y = pk2(v.z * QSCALE, v.w * QSCALE);
            *(uint2*)&sQ[r][c4] = u;
        }
    }
    __syncthreads();
    short8 qreg[4];
    {
        unsigned short (*sQ)[SD] = (unsigned short (*)[SD])lds;
#pragma unroll
        for (int ks = 0; ks < 4; ++ks)
            qreg[ks] = *(const short8*)&sQ[qg * 32 + l31][ks * 16 + h * 8];
    }
    __syncthreads();

    float4 kA, kB, vA, vB;
    auto issue = [&](int kv0) {
        kA = *(const float4*)(Kp + (size_t)(kv0 + r0) * HD + c4);
        kB = *(const float4*)(Kp + (size_t)(kv0 + 32 + r0) * HD + c4);
        vA = *(const float4*)(Vp + (size_t)(kv0 + RA + qd) * HD + c4);
        vB = *(const float4*)(Vp + (size_t)(kv0 + 32 + RA + qd) * HD + c4);
    };
    auto vstore = [&](float4 vf, int R, int buf) {
        float e0 = vf.x, e1 = vf.y, e2 = vf.z, e3 = vf.w;
        float s0 = (qd & 2) ? e0 : e2;
        float s1 = (qd & 2) ? e1 : e3;
        s0 = __shfl_xor(s0, 32); s1 = __shfl_xor(s1, 32);
        if (qd & 2) { e0 = s0; e1 = s1; } else { e2 = s0; e3 = s1; }
        s0 = (qd & 1) ? e0 : e1;
        s1 = (qd & 1) ? e2 : e3;
        s0 = __shfl_xor(s0, 16); s1 = __shfl_xor(s1, 16);
        if (qd & 1) { e0 = s0; e2 = s1; } else { e1 = s0; e3 = s1; }
        const int d   = c4 + qd;
        const int col = ((((R >> 3) ^ (d >> 3)) & 7) << 3) | (R & 7);
        uint2 u; u.x = pk2(e0, e1); u.y = pk2(e2, e3);
        *(uint2*)&sVt[buf][d][col] = u;
    };
    auto commit = [&](int buf) {
        { uint2 u; u.x = pk2(kA.x, kA.y); u.y = pk2(kA.z, kA.w);
          *(uint2*)&sK[buf][r0][c4] = u; }
        { uint2 u; u.x = pk2(kB.x, kB.y); u.y = pk2(kB.z, kB.w);
          *(uint2*)&sK[buf][32 + r0][c4] = u; }
        vstore(vA, RA, buf);
        vstore(vB, 32 + RA, buf);
    };

    f32x16 accO[2];
#pragma unroll
    for (int r = 0; r < 16; ++r) { accO[0][r] = 0.f; accO[1][r] = 0.f; }
    float lsum = 0.f;

    const int qminw = q0 + qg * 32;
    const int qmaxw = qminw + 31;
    const int n_it  = (q0 + BM) / BN;

    issue(0);
    commit(0);

    for (int it = 0; it < n_it; ++it) {
        const int kv0 = it * BN;
        const int buf = it & 1;
        __syncthreads();
        const bool more = (it + 1 < n_it);
        if (more) issue(kv0 + BN);

        if (kv0 + kh * 32 <= qmaxw) {
            f32x16 accS;
#pragma unroll
            for (int r = 0; r < 16; ++r) accS[r] = 0.f;
            __builtin_amdgcn_s_setprio(1);
#pragma unroll
            for (int ks = 0; ks < 4; ++ks) {
                const short8 ak = *(const short8*)&sK[buf][kh * 32 + l31][ks * 16 + h * 8];
                accS = __builtin_amdgcn_mfma_f32_32x32x16_bf16(ak, qreg[ks], accS, 0, 0, 0);
            }
            __builtin_amdgcn_s_setprio(0);

            if (kv0 + kh * 32 + 31 > qminw) {
                const int qrow = qminw + l31;
                const int kvb  = kv0 + kh * 32 + 4 * h;
#pragma unroll
                for (int r = 0; r < 16; ++r) {
                    const int kv = kvb + (r & 3) + 8 * (r >> 2);
                    if (kv > qrow) accS[r] = -1e30f;
                }
            }
#pragma unroll
            for (int r = 0; r < 16; ++r) {
                const float p = __builtin_amdgcn_exp2f(accS[r]);
                accS[r] = p;
                lsum += p;
            }
            short8 pf[2];
#pragma unroll
            for (int s = 0; s < 2; ++s) {
                const int rb = s * 8;
                const unsigned a0 = pk2(accS[rb + 0], accS[rb + 1]);
                const unsigned b0 = pk2(accS[rb + 4], accS[rb + 5]);
                const unsigned a1 = pk2(accS[rb + 2], accS[rb + 3]);
                const unsigned b1 = pk2(accS[rb + 6], accS[rb + 7]);
                const auto r02 = __builtin_amdgcn_permlane32_swap(a0, b0, 0, 0);
                const auto r13 = __builtin_amdgcn_permlane32_swap(a1, b1, 0, 0);
                union { unsigned u[4]; short8 s8; } pu;
                pu.u[0] = r02[0]; pu.u[1] = r13[0]; pu.u[2] = r02[1]; pu.u[3] = r13[1];
                pf[s] = pu.s8;
            }
            __builtin_amdgcn_s_setprio(1);
#pragma unroll
            for (int s = 0; s < 2; ++s) {
                const int K0 = kh * 32 + s * 16 + h * 8;
#pragma unroll
                for (int dg = 0; dg < 2; ++dg) {
                    const int d   = dg * 32 + l31;
                    const int col = (((K0 >> 3) ^ (d >> 3)) & 7) << 3;
                    const short8 av = *(const short8*)&sVt[buf][d][col];
                    accO[dg] = __builtin_amdgcn_mfma_f32_32x32x16_bf16(av, pf[s], accO[dg], 0, 0, 0);
                }
            }
            __builtin_amdgcn_s_setprio(0);
        }

        if (more) commit(buf ^ 1);
    }

    lsum += __shfl_xor(lsum, 32);
    __syncthreads();
    float* fx  = (float*)lds;
    float* fla = fx + 4 * 64 * 32;
    if (kh == 1) {
#pragma unroll
        for (int dg = 0; dg < 2; ++dg) {
#pragma unroll
            for (int r = 0; r < 16; ++r) {
                const int d = dg * 32 + (r & 3) + 8 * (r >> 2) + 4 * h;
                fx[(qg * 64 + d) * 32 + l31] = accO[dg][r];
            }
        }
        if (h == 0) fla[qg * 32 + l31] = lsum;
    }
    __syncthreads();
    if (kh == 0) {
        const float inv  = 1.0f / (lsum + fla[qg * 32 + l31]);
        const int   qrow = q0 + qg * 32 + l31;
        float* Op = Og + base + (size_t)qrow * HD;
#pragma unroll
        for (int dg = 0; dg < 2; ++dg) {
#pragma unroll
            for (int rq = 0; rq < 4; ++rq) {
                const int d = dg * 32 + 8 * rq + 4 * h;
                const float* fr = &fx[(qg * 64 + d) * 32 + l31];
                float4 o;
                o.x = (accO[dg][rq * 4 + 0] + fr[0])  * inv;
                o.y = (accO[dg][rq * 4 + 1] + fr[32]) * inv;
                o.z = (accO[dg][rq * 4 + 2] + fr[64]) * inv;
                o.w = (accO[dg][rq * 4 + 3] + fr[96]) * inv;
                *(float4*)(Op + d) = o;
            }
        }
    }
}

extern "C" void kernel_launch(void* const* d_in, const int* in_sizes, int n_in,
                              void* d_out, int out_size, void* d_ws, size_t ws_size,
                              hipStream_t stream) {
    const float* Q = (const float*)d_in[0];
    const float* K = (const float*)d_in[1];
    const float* V = (const float*)d_in[2];
    float* O = (float*)d_out;
    if (d_ws != nullptr && ws_size >= WS_NEEDED) {
        unsigned short* KF = (unsigned short*)d_ws;
        unsigned short* VF = KF + WS_HALF;
        prep<<<dim3(1024), dim3(256), 0, stream>>>(K, V, KF, VF);
        fa_main<<<dim3(512), dim3(512), 0, stream>>>(Q, KF, VF, O);
    } else {
        fa_fwd<<<dim3(512), dim3(512), 0, stream>>>(Q, K, V, O);
    }
}

// Round 12
// 116.852 us; speedup vs baseline: 1.1750x; 1.1750x over previous
//
#include <hip/hip_runtime.h>
#include <hip/hip_bf16.h>

#define BM 128
#define BN 64
#define HD 64
#define LQ 2048
#define SD 72

typedef __attribute__((ext_vector_type(8))) short short8;
typedef __attribute__((ext_vector_type(16))) float f32x16;

// Q pre-scale: 1/sqrt(16) * log2(e) -> scores in log2 domain
#define QSCALE 0.360673760222241f

// workspace: KF | VF, each bf16 [32 heads][64 ch][4 units][64 lanes][8] = 32*2048*64
#define WS_HALF  ((size_t)32 * 2048 * 64)           // elements (ushort)
#define WS_NEEDED (2 * WS_HALF * sizeof(unsigned short))

static __device__ __forceinline__ unsigned pk2(float a, float b) {
    union { __hip_bfloat162 h2; unsigned u; } c;
    c.h2 = __float22bfloat162_rn(make_float2(a, b));   // v_cvt_pk_bf16_f32
    return c.u;
}

// ---------------- prepass: K,V -> bf16 fragment-ready layout (verified R7/R8) ----------------
// KF unit (ch, ks, lane): K[ch*32 + (lane&31)][ks*16 + (lane>>5)*8 .. +8]
// VF unit (ch, u=s*2+dg, lane): V^T[dg*32+(lane&31)][ch*32 + s*16 + (lane>>5)*8 .. +8]
__global__ __launch_bounds__(256)
void prep(const float* __restrict__ Kg, const float* __restrict__ Vg,
          unsigned short* __restrict__ KF, unsigned short* __restrict__ VF) {
    __shared__ unsigned short sK2[64][72];
    __shared__ unsigned short sV2[64][72];
    const int t  = threadIdx.x;
    const int bx = blockIdx.x;
    const int bh = bx >> 5;
    const int c  = bx & 31;
    const size_t ibase = (size_t)bh * (LQ * HD) + (size_t)c * 64 * HD;
    const int r  = t >> 4;
    const int c4 = (t & 15) * 4;

#pragma unroll
    for (int p = 0; p < 4; ++p) {
        const int row = p * 16 + r;
        const float4 kv4 = *(const float4*)(Kg + ibase + (size_t)row * HD + c4);
        uint2 ku; ku.x = pk2(kv4.x, kv4.y); ku.y = pk2(kv4.z, kv4.w);
        *(uint2*)&sK2[row][c4] = ku;
        const float4 vv4 = *(const float4*)(Vg + ibase + (size_t)row * HD + c4);
        const unsigned u0 = pk2(vv4.x, vv4.y);
        const unsigned u1 = pk2(vv4.z, vv4.w);
        sV2[c4 + 0][row] = (unsigned short)(u0 & 0xffff);
        sV2[c4 + 1][row] = (unsigned short)(u0 >> 16);
        sV2[c4 + 2][row] = (unsigned short)(u1 & 0xffff);
        sV2[c4 + 3][row] = (unsigned short)(u1 >> 16);
    }
    __syncthreads();

    const int lane = t & 63;
    const int u    = t >> 6;
    const int l31  = lane & 31;
    const int hh   = lane >> 5;
#pragma unroll
    for (int e = 0; e < 2; ++e) {
        const int ch = 2 * c + e;
        const size_t ob = ((size_t)(bh * 64 + ch) * 4 + u) * 512 + lane * 8;
        *(uint4*)&KF[ob] = *(const uint4*)&sK2[e * 32 + l31][u * 16 + hh * 8];
        *(uint4*)&VF[ob] = *(const uint4*)&sV2[(u & 1) * 32 + l31][e * 32 + (u >> 1) * 16 + hh * 8];
    }
}

// ---------------- main: R9 pipeline, 256-thr blocks x 1024 for smooth residency ----------------
// Block (bh, g): 4 waves = qg(0..1) x kp(0..1). q-block j = 2*qt + qg; wave handles
// chunks ch ≡ kp (mod 2), ch <= j. Co-resident CU group {g, g+8, g+16, g+24}: qt sums 62.
__global__ __launch_bounds__(256, 4)
void fa_main(const float* __restrict__ Qg,
             const unsigned short* __restrict__ KF,
             const unsigned short* __restrict__ VF,
             float* __restrict__ Og) {
    // LDS only for the final parity-combine: [2 qg][64 d][32 q] + denoms
    __shared__ float fx[2 * 64 * 32];
    __shared__ float fla[2 * 32];

    const int t    = threadIdx.x;
    const int w    = t >> 6;            // wave 0..3
    const int lane = t & 63;
    const int h    = lane >> 5;
    const int l31  = lane & 31;
    const int qg   = w & 1;             // q-group: 32 rows
    const int kp   = w >> 1;            // kv parity: chunks ch ≡ kp (mod 2)

    // g -> qt: co-resident groups {g, g+8, g+16, g+24} have qt sums = 62 (LPT, long first)
    const int bx = blockIdx.x;
    const int bh = bx & 31;             // head; all blocks of a head share an XCD residue
    const int g  = bx >> 5;             // 0..31
    const int a  = g & 7, b = g >> 3;
    const int qt = (b == 0) ? (31 - 2 * a)
                 : (b == 1) ? (2 * a)
                 : (b == 2) ? (30 - 2 * a)
                 :            (2 * a + 1);

    const size_t base = (size_t)bh * (LQ * HD);
    const unsigned short* KFh = KF + (size_t)bh * 131072 + lane * 8;
    const unsigned short* VFh = VF + (size_t)bh * 131072 + lane * 8;

    const int j    = 2 * qt + qg;       // global q-block 0..63
    const int qrow = j * 32 + l31;

    // ---- Q fragments direct from global fp32, pre-scaled (loop-invariant) ----
    short8 qreg[4];
    {
        const float* Qrow = Qg + base + (size_t)qrow * HD;
#pragma unroll
        for (int ks = 0; ks < 4; ++ks) {
            const float4 a4 = *(const float4*)(Qrow + ks * 16 + h * 8);
            const float4 b4 = *(const float4*)(Qrow + ks * 16 + h * 8 + 4);
            union { unsigned u[4]; short8 s8; } qu;
            qu.u[0] = pk2(a4.x * QSCALE, a4.y * QSCALE);
            qu.u[1] = pk2(a4.z * QSCALE, a4.w * QSCALE);
            qu.u[2] = pk2(b4.x * QSCALE, b4.y * QSCALE);
            qu.u[3] = pk2(b4.z * QSCALE, b4.w * QSCALE);
            qreg[ks] = qu.s8;
        }
    }

    f32x16 accO[2];
#pragma unroll
    for (int r = 0; r < 16; ++r) { accO[0][r] = 0.f; accO[1][r] = 0.f; }
    float lsum0 = 0.f, lsum1 = 0.f;     // split serial add chain

    // single-buffer pipeline state (R9-verified)
    short8 ak[4], av[4], pf[2];
    f32x16 accS;

    auto loadK = [&](int ch) {
        const unsigned short* p = KFh + (size_t)ch * 2048;
        ak[0] = *(const short8*)(p);
        ak[1] = *(const short8*)(p + 512);
        ak[2] = *(const short8*)(p + 1024);
        ak[3] = *(const short8*)(p + 1536);
    };
    auto loadV = [&](int ch) {
        const unsigned short* p = VFh + (size_t)ch * 2048;
        av[0] = *(const short8*)(p);
        av[1] = *(const short8*)(p + 512);
        av[2] = *(const short8*)(p + 1024);
        av[3] = *(const short8*)(p + 1536);
    };
    auto qkt = [&]() {                  // S^T[32kv][32q] = K * Q^T (log2 domain)
#pragma unroll
        for (int r = 0; r < 16; ++r) accS[r] = 0.f;
        __builtin_amdgcn_s_setprio(1);
#pragma unroll
        for (int ks = 0; ks < 4; ++ks)
            accS = __builtin_amdgcn_mfma_f32_32x32x16_bf16(ak[ks], qreg[ks], accS, 0, 0, 0);
        __builtin_amdgcn_s_setprio(0);
    };
    auto smpk = [&](int pc) {           // mask(if diagonal) + exp2 + denom + pack -> pf
        if (pc == j) {
            const int kvb = pc * 32 + 4 * h;
#pragma unroll
            for (int r = 0; r < 16; ++r) {
                const int kv = kvb + (r & 3) + 8 * (r >> 2);
                if (kv > qrow) accS[r] = -1e30f;
            }
        }
#pragma unroll
        for (int r = 0; r < 16; ++r) {
            const float p = __builtin_amdgcn_exp2f(accS[r]);
            accS[r] = p;
            if (r & 1) lsum1 += p; else lsum0 += p;
        }
#pragma unroll
        for (int s = 0; s < 2; ++s) {
            const int rb = s * 8;
            const unsigned a0 = pk2(accS[rb + 0], accS[rb + 1]);
            const unsigned b0 = pk2(accS[rb + 4], accS[rb + 5]);
            const unsigned a1 = pk2(accS[rb + 2], accS[rb + 3]);
            const unsigned b1 = pk2(accS[rb + 6], accS[rb + 7]);
            const auto r02 = __builtin_amdgcn_permlane32_swap(a0, b0, 0, 0);
            const auto r13 = __builtin_amdgcn_permlane32_swap(a1, b1, 0, 0);
            union { unsigned u[4]; short8 s8; } pu;
            pu.u[0] = r02[0]; pu.u[1] = r13[0]; pu.u[2] = r02[1]; pu.u[3] = r13[1];
            pf[s] = pu.s8;
        }
    };
    auto pv = [&]() {                   // O^T += V^T * P^T
        __builtin_amdgcn_s_setprio(1);
#pragma unroll
        for (int s = 0; s < 2; ++s)
#pragma unroll
            for (int dg = 0; dg < 2; ++dg)
                accO[dg] = __builtin_amdgcn_mfma_f32_32x32x16_bf16(av[s * 2 + dg], pf[s], accO[dg], 0, 0, 0);
        __builtin_amdgcn_s_setprio(0);
    };

    // ---- deferred-softmax pipeline: phase(ch) = {loadK(ch) | smpk(pc) | pv(pc) | loadV(ch) | qkt(ch)} ----
    int ch = kp;
    if (ch <= j) {
        loadK(ch);
        loadV(ch);
        qkt();                           // K latency exposed once per wave
        int pc = ch;
        ch += 2;
        while (ch <= j) {
            loadK(ch);                   // in flight under smpk+pv
            __builtin_amdgcn_sched_barrier(0);
            smpk(pc);                    // never diagonal in-loop
            pv();
            loadV(ch);                   // in flight until next phase's pv
            __builtin_amdgcn_sched_barrier(0);
            qkt();                       // consumes ak = K(ch), covered
            pc = ch;
            ch += 2;
        }
        smpk(pc);                        // tail: diagonal mask applies here
        pv();
    }

    // ---- epilogue: combine parities via LDS (R8-verified pattern) ----
    float lsum = lsum0 + lsum1;
    lsum += __shfl_xor(lsum, 32);
    if (kp == 1) {
#pragma unroll
        for (int dg = 0; dg < 2; ++dg) {
#pragma unroll
            for (int r = 0; r < 16; ++r) {
                const int d = dg * 32 + (r & 3) + 8 * (r >> 2) + 4 * h;
                fx[(qg * 64 + d) * 32 + l31] = accO[dg][r];
            }
        }
        if (h == 0) fla[qg * 32 + l31] = lsum;
    }
    __syncthreads();
    if (kp == 0) {
        const float inv = 1.0f / (lsum + fla[qg * 32 + l31]);
        float* Op = Og + base + (size_t)qrow * HD;
#pragma unroll
        for (int dg = 0; dg < 2; ++dg) {
#pragma unroll
            for (int rq = 0; rq < 4; ++rq) {
                const int d = dg * 32 + 8 * rq + 4 * h;
                const float* fr = &fx[(qg * 64 + d) * 32 + l31];
                float4 o;
                o.x = (accO[dg][rq * 4 + 0] + fr[0])  * inv;
                o.y = (accO[dg][rq * 4 + 1] + fr[32]) * inv;
                o.z = (accO[dg][rq * 4 + 2] + fr[64]) * inv;
                o.w = (accO[dg][rq * 4 + 3] + fr[96]) * inv;
                *(float4*)(Op + d) = o;
            }
        }
    }
}

// ---------------- fallback: R1 kernel (verified 54.6 us), used if ws too small ----------------
__global__ __launch_bounds__(512, 4)
void fa_fwd(const float* __restrict__ Qg,
            const float* __restrict__ Kg,
            const float* __restrict__ Vg,
            float* __restrict__ Og) {
    __shared__ __align__(16) unsigned short lds[(2 * BN + 2 * HD) * SD];
    typedef unsigned short KT[BN][SD];
    typedef unsigned short VT[HD][SD];
    KT* sK  = (KT*)lds;
    VT* sVt = (VT*)(lds + 2 * BN * SD);

    const int t    = threadIdx.x;
    const int w    = t >> 6;
    const int lane = t & 63;
    const int h    = lane >> 5;
    const int l31  = lane & 31;
    const int qd   = lane >> 4;
    const int qg   = w & 3;
    const int kh   = w >> 2;

    const int bx  = blockIdx.x;
    const int idx = (bx >> 5) & 7;
    const int qt  = (bx & 256) ? idx : (15 - idx);
    const int bh  = bx & 31;
    const int q0  = qt * BM;

    const size_t base = (size_t)bh * (LQ * HD);
    const float* Qp = Qg + base + (size_t)q0 * HD;
    const float* Kp = Kg + base;
    const float* Vp = Vg + base;

    const int r0 = t >> 4;
    const int c4 = (t & 15) * 4;
    const int RA = w * 4;

    {
        unsigned short (*sQ)[SD] = (unsigned short (*)[SD])lds;
#pragma unroll
        for (int p = 0; p < 4; ++p) {
            const int r = p * 32 + r0;
            const float4 v = *(const float4*)(Qp + (size_t)r * HD + c4);
            uint2 u;
            u.x = pk2(v.x * QSCALE, v.y * QSCALE);
            u.y = pk2(v.z * QSCALE, v.w * QSCALE);
            *(uint2*)&sQ[r][c4] = u;
        }
    }
    __syncthreads();
    short8 qreg[4];
    {
        unsigned short (*sQ)[SD] = (unsigned short (*)[SD])lds;
#pragma unroll
        for (int ks = 0; ks < 4; ++ks)
            qreg[ks] = *(const short8*)&sQ[qg * 32 + l31][ks * 16 + h * 8];
    }
    __syncthreads();

    float4 kA, kB, vA, vB;
    auto issue = [&](int kv0) {
        kA = *(const float4*)(Kp + (size_t)(kv0 + r0) * HD + c4);
        kB = *(const float4*)(Kp + (size_t)(kv0 + 32 + r0) * HD + c4);
        vA = *(const float4*)(Vp + (size_t)(kv0 + RA + qd) * HD + c4);
        vB = *(const float4*)(Vp + (size_t)(kv0 + 32 + RA + qd) * HD + c4);
    };
    auto vstore = [&](float4 vf, int R, int buf) {
        float e0 = vf.x, e1 = vf.y, e2 = vf.z, e3 = vf.w;
        float s0 = (qd & 2) ? e0 : e2;
        float s1 = (qd & 2) ? e1 : e3;
        s0 = __shfl_xor(s0, 32); s1 = __shfl_xor(s1, 32);
        if (qd & 2) { e0 = s0; e1 = s1; } else { e2 = s0; e3 = s1; }
        s0 = (qd & 1) ? e0 : e1;
        s1 = (qd & 1) ? e2 : e3;
        s0 = __shfl_xor(s0, 16); s1 = __shfl_xor(s1, 16);
        if (qd & 1) { e0 = s0; e2 = s1; } else { e1 = s0; e3 = s1; }
        const int d   = c4 + qd;
        const int col = ((((R >> 3) ^ (d >> 3)) & 7) << 3) | (R & 7);
        uint2 u; u.x = pk2(e0, e1); u.y = pk2(e2, e3);
        *(uint2*)&sVt[buf][d][col] = u;
    };
    auto commit = [&](int buf) {
        { uint2 u; u.x = pk2(kA.x, kA.y); u.y = pk2(kA.z, kA.w);
          *(uint2*)&sK[buf][r0][c4] = u; }
        { uint2 u; u.x = pk2(kB.x, kB.y); u.y = pk2(kB.z, kB.w);
          *(uint2*)&sK[buf][32 + r0][c4] = u; }
        vstore(vA, RA, buf);
        vstore(vB, 32 + RA, buf);
    };

    f32x16 accO[2];
#pragma unroll
    for (int r = 0; r < 16; ++r) { accO[0][r] = 0.f; accO[1][r] = 0.f; }
    float lsum = 0.f;

    const int qminw = q0 + qg * 32;
    const int qmaxw = qminw + 31;
    const int n_it  = (q0 + BM) / BN;

    issue(0);
    commit(0);

    for (int it = 0; it < n_it; ++it) {
        const int kv0 = it * BN;
        const int buf = it & 1;
        __syncthreads();
        const bool more = (it + 1 < n_it);
        if (more) issue(kv0 + BN);

        if (kv0 + kh * 32 <= qmaxw) {
            f32x16 accS;
#pragma unroll
            for (int r = 0; r < 16; ++r) accS[r] = 0.f;
            __builtin_amdgcn_s_setprio(1);
#pragma unroll
            for (int ks = 0; ks < 4; ++ks) {
                const short8 ak = *(const short8*)&sK[buf][kh * 32 + l31][ks * 16 + h * 8];
                accS = __builtin_amdgcn_mfma_f32_32x32x16_bf16(ak, qreg[ks], accS, 0, 0, 0);
            }
            __builtin_amdgcn_s_setprio(0);

            if (kv0 + kh * 32 + 31 > qminw) {
                const int qrow = qminw + l31;
                const int kvb  = kv0 + kh * 32 + 4 * h;
#pragma unroll
                for (int r = 0; r < 16; ++r) {
                    const int kv = kvb + (r & 3) + 8 * (r >> 2);
                    if (kv > qrow) accS[r] = -1e30f;
                }
            }
#pragma unroll
            for (int r = 0; r < 16; ++r) {
                const float p = __builtin_amdgcn_exp2f(accS[r]);
                accS[r] = p;
                lsum += p;
            }
            short8 pf[2];
#pragma unroll
            for (int s = 0; s < 2; ++s) {
                const int rb = s * 8;
                const unsigned a0 = pk2(accS[rb + 0], accS[rb + 1]);
                const unsigned b0 = pk2(accS[rb + 4], accS[rb + 5]);
                const unsigned a1 = pk2(accS[rb + 2], accS[rb + 3]);
                const unsigned b1 = pk2(accS[rb + 6], accS[rb + 7]);
                const auto r02 = __builtin_amdgcn_permlane32_swap(a0, b0, 0, 0);
                const auto r13 = __builtin_amdgcn_permlane32_swap(a1, b1, 0, 0);
                union { unsigned u[4]; short8 s8; } pu;
                pu.u[0] = r02[0]; pu.u[1] = r13[0]; pu.u[2] = r02[1]; pu.u[3] = r13[1];
                pf[s] = pu.s8;
            }
            __builtin_amdgcn_s_setprio(1);
#pragma unroll
            for (int s = 0; s < 2; ++s) {
                const int K0 = kh * 32 + s * 16 + h * 8;
#pragma unroll
                for (int dg = 0; dg < 2; ++dg) {
                    const int d   = dg * 32 + l31;
                    const int col = (((K0 >> 3) ^ (d >> 3)) & 7) << 3;
                    const short8 av = *(const short8*)&sVt[buf][d][col];
                    accO[dg] = __builtin_amdgcn_mfma_f32_32x32x16_bf16(av, pf[s], accO[dg], 0, 0, 0);
                }
            }
            __builtin_amdgcn_s_setprio(0);
        }

        if (more) commit(buf ^ 1);
    }

    lsum += __shfl_xor(lsum, 32);
    __syncthreads();
    float* fx  = (float*)lds;
    float* fla = fx + 4 * 64 * 32;
    if (kh == 1) {
#pragma unroll
        for (int dg = 0; dg < 2; ++dg) {
#pragma unroll
            for (int r = 0; r < 16; ++r) {
                const int d = dg * 32 + (r & 3) + 8 * (r >> 2) + 4 * h;
                fx[(qg * 64 + d) * 32 + l31] = accO[dg][r];
            }
        }
        if (h == 0) fla[qg * 32 + l31] = lsum;
    }
    __syncthreads();
    if (kh == 0) {
        const float inv  = 1.0f / (lsum + fla[qg * 32 + l31]);
        const int   qrow = q0 + qg * 32 + l31;
        float* Op = Og + base + (size_t)qrow * HD;
#pragma unroll
        for (int dg = 0; dg < 2; ++dg) {
#pragma unroll
            for (int rq = 0; rq < 4; ++rq) {
                const int d = dg * 32 + 8 * rq + 4 * h;
                const float* fr = &fx[(qg * 64 + d) * 32 + l31];
                float4 o;
                o.x = (accO[dg][rq * 4 + 0] + fr[0])  * inv;
                o.y = (accO[dg][rq * 4 + 1] + fr[32]) * inv;
                o.z = (accO[dg][rq * 4 + 2] + fr[64]) * inv;
                o.w = (accO[dg][rq * 4 + 3] + fr[96]) * inv;
                *(float4*)(Op + d) = o;
            }
        }
    }
}

extern "C" void kernel_launch(void* const* d_in, const int* in_sizes, int n_in,
                              void* d_out, int out_size, void* d_ws, size_t ws_size,
                              hipStream_t stream) {
    const float* Q = (const float*)d_in[0];
    const float* K = (const float*)d_in[1];
    const float* V = (const float*)d_in[2];
    float* O = (float*)d_out;
    if (d_ws != nullptr && ws_size >= WS_NEEDED) {
        unsigned short* KF = (unsigned short*)d_ws;
        unsigned short* VF = KF + WS_HALF;
        prep<<<dim3(1024), dim3(256), 0, stream>>>(K, V, KF, VF);
        fa_main<<<dim3(1024), dim3(256), 0, stream>>>(Q, KF, VF, O);
    } else {
        fa_fwd<<<dim3(512), dim3(512), 0, stream>>>(Q, K, V, O);
    }
}